// Round 1
// baseline (663.271 us; speedup 1.0000x reference)
//
#include <hip/hip_runtime.h>
#include <math.h>

#define VOCAB   10003
#define NITEMS  10000
#define PADTOK  10000
#define BB      4
#define SS      128
#define BLK     512
#define VC      4
#define NB      5   // NB*VC*BLK = 10240 >= NITEMS

#if __has_builtin(__builtin_amdgcn_exp2f)
#define EXP2F(x) __builtin_amdgcn_exp2f(x)
#else
#define EXP2F(x) exp2f(x)
#endif
#if __has_builtin(__builtin_amdgcn_rcpf)
#define RCPF(x) __builtin_amdgcn_rcpf(x)
#else
#define RCPF(x) (1.0f/(x))
#endif

__device__ __forceinline__ float gelu_fast(float t) {
    // gelu_tanh(t) = t * (1 - 1/(1+exp(2z))), z = 0.7978845608*(t + 0.044715 t^3)
    // q = 2*z*log2(e) = t*(GC0 + GC1*t^2)
    const float GC0 = 2.3022080f;     // 2*0.7978845608*log2(e)
    const float GC1 = 0.10294325f;    // GC0*0.044715
    float t2 = t * t;
    float q  = t * fmaf(t2, GC1, GC0);
    float e  = EXP2F(q);
    float r  = RCPF(1.0f + e);
    return fmaf(-t, r, t);            // t*(1-r)
}

__global__ __launch_bounds__(BLK, 2) void bbm_kernel(
    const int*   __restrict__ seqs,   // (B,S)
    const int*   __restrict__ labels, // (B,S)
    const float* __restrict__ Tsrc,   // (VOCAB,VOCAB)
    const float* __restrict__ Tdst,   // (VOCAB,VOCAB)
    const float* __restrict__ pop,    // (VOCAB,)
    const float* __restrict__ pn,     // (VOCAB,) normalized
    const float* __restrict__ W1,     // (3,32)
    const float* __restrict__ b1,     // (32,)
    const float* __restrict__ W2,     // (32,1)
    float*       __restrict__ out)    // (B*S,)
{
    __shared__ float4 wA[32];             // (W1[0][j], W1[1][j], W1[2][j], b1[j])
    __shared__ float  wB[32];             // W2[j]
    __shared__ float red_m[8], red_s[8], red_l[8];

    const int tid = threadIdx.x;
    if (tid < 32) {
        wA[tid] = make_float4(W1[tid], W1[32 + tid], W1[64 + tid], b1[tid]);
        wB[tid] = W2[tid];
    }

    const int t  = blockIdx.x;
    const int bb = t >> 7;        // t / S
    const int ss = t & (SS - 1);  // t % S

    int raw_src = (ss == 0)      ? PADTOK : seqs[bb * SS + ss - 1];
    int raw_dst = (ss == SS - 1) ? PADTOK : seqs[bb * SS + ss + 1];
    if (raw_src < 0) raw_src = 0;   // seqs = max(masked,0) before shifting
    if (raw_dst < 0) raw_dst = 0;
    const float* __restrict__ srow = Tsrc + (size_t)raw_src * VOCAB;
    const float* __restrict__ drow = Tdst + (size_t)raw_dst * VOCAB;

    const int  lbl   = labels[t];
    const bool valid = (lbl != -100);
    const int  lv    = (lbl < 0) ? 0 : lbl;

    __syncthreads();

    const float L2E = 1.4426950408889634f;
    float m  = -INFINITY;   // running max
    float sm = 0.0f;        // running sum of exp
    float bl = -INFINITY;   // logit at label (reduced via max)

    for (int batch = 0; batch < NB; ++batch) {
        float x0[VC], x1[VC], pv2[VC], acc[VC];
        int   vv[VC];
        bool  in[VC];
        #pragma unroll
        for (int k = 0; k < VC; ++k) {
            const int v = (batch * VC + k) * BLK + tid;
            vv[k] = v;
            in[k] = (v < NITEMS);
            const float sv  = in[k] ? srow[v] : 0.0f;
            const float dv  = in[k] ? drow[v] : 0.0f;
            const float pv  = in[k] ? pop[v]  : 1.0f;
            const float pnv = in[k] ? pn[v]   : 0.0f;
            const float rp  = (pv != 0.0f) ? RCPF(pv) : 0.0f;  // div_no_nan
            x0[k]  = sv * rp;
            x1[k]  = dv * rp;
            pv2[k] = pnv;
            acc[k] = 0.0f;
        }

        #pragma unroll
        for (int j = 0; j < 32; ++j) {
            const float4 w  = wA[j];
            const float  w2 = wB[j];
            #pragma unroll
            for (int k = 0; k < VC; ++k) {
                float tt = fmaf(x0[k], w.x, fmaf(x1[k], w.y, fmaf(pv2[k], w.z, w.w)));
                float h  = gelu_fast(tt);
                acc[k]   = fmaf(h, w2, acc[k]);
            }
        }

        float bias[VC];
        #pragma unroll
        for (int k = 0; k < VC; ++k) {
            bias[k] = in[k] ? acc[k] : -1e30f;
            if (vv[k] == lv) bl = acc[k];   // lv < NITEMS always
        }

        // online softmax update (chunk max first: single rescale)
        float cm = fmaxf(fmaxf(bias[0], bias[1]), fmaxf(bias[2], bias[3]));
        float mn = fmaxf(m, cm);
        float scale = EXP2F((m - mn) * L2E);   // m=-inf on first batch -> 0, sm=0
        float a2 = 0.0f;
        #pragma unroll
        for (int k = 0; k < VC; ++k) a2 += EXP2F((bias[k] - mn) * L2E);
        sm = fmaf(sm, scale, a2);
        m  = mn;
    }

    // wave (64-lane) reduction of (m, sm) and bl
    #pragma unroll
    for (int off = 32; off >= 1; off >>= 1) {
        float m2 = __shfl_down(m, off);
        float s2 = __shfl_down(sm, off);
        float l2 = __shfl_down(bl, off);
        float mn = fmaxf(m, m2);
        sm = sm * EXP2F((m - mn) * L2E) + s2 * EXP2F((m2 - mn) * L2E);
        m  = mn;
        bl = fmaxf(bl, l2);
    }
    const int wid  = tid >> 6;
    const int lane = tid & 63;
    if (lane == 0) { red_m[wid] = m; red_s[wid] = sm; red_l[wid] = bl; }
    __syncthreads();

    if (tid == 0) {
        float M = red_m[0], Sm = red_s[0], L = red_l[0];
        #pragma unroll
        for (int w = 1; w < 8; ++w) {
            float m2 = red_m[w], s2 = red_s[w], l2 = red_l[w];
            float mn = fmaxf(M, m2);
            Sm = Sm * EXP2F((M - mn) * L2E) + s2 * EXP2F((m2 - mn) * L2E);
            M  = mn;
            L  = fmaxf(L, l2);
        }
        float lse = M + __logf(Sm);   // b2 cancels in lse - L
        out[t] = valid ? (lse - L) : 0.0f;
    }
}

extern "C" void kernel_launch(void* const* d_in, const int* in_sizes, int n_in,
                              void* d_out, int out_size, void* d_ws, size_t ws_size,
                              hipStream_t stream) {
    const int*   seqs   = (const int*)  d_in[0];
    const int*   labels = (const int*)  d_in[1];
    const float* Tsrc   = (const float*)d_in[2];
    const float* Tdst   = (const float*)d_in[3];
    const float* pop    = (const float*)d_in[4];
    const float* pn     = (const float*)d_in[5];
    const float* W1     = (const float*)d_in[6];
    const float* b1     = (const float*)d_in[7];
    const float* W2     = (const float*)d_in[8];
    float*       out    = (float*)      d_out;

    bbm_kernel<<<BB * SS, BLK, 0, stream>>>(seqs, labels, Tsrc, Tdst, pop, pn,
                                            W1, b1, W2, out);
}